// Round 8
// baseline (265.725 us; speedup 1.0000x reference)
//
#include <hip/hip_runtime.h>
#include <math.h>

namespace {
constexpr int kB  = 64, kT = 1024, kK = 512;
constexpr int kC  = 32;             // chunks along T
constexpr int kL  = kT / kC;        // 32 steps per chunk
constexpr int kQ  = kK / 4;         // 128 float4-groups along K
constexpr int kTh = 256;            // threads per block
constexpr int kG  = kB * kC * kQ;   // 262144 threads for k1/k3
constexpr float kDT = 0.001f;
}

// Native vector type for nontemporal stores (HIP float4 is a class type
// that __builtin_nontemporal_store rejects; this is layout-identical).
typedef float nt4 __attribute__((ext_vector_type(4)));

__device__ __forceinline__ void nt_store4(float4 v, float4* p) {
    nt4 w; w.x = v.x; w.y = v.y; w.z = v.z; w.w = v.w;
    __builtin_nontemporal_store(w, (nt4*)p);
}

// Per-feature coefficients (identical arithmetic to the reference).
__device__ __forceinline__ void alpha_coeffs(float tk,
    float& a00, float& a01, float& a10, float& a11, float& b0, float& b1)
{
    const float tc      = fmaxf(tk, 1e-8f);
    const float dt_tau  = kDT / tc;
    const float dt_tau2 = dt_tau / tc;
    const float e       = expf(-dt_tau);
    a00 = e * (1.0f - dt_tau);
    a01 = e * (-dt_tau2);
    a10 = e * kDT;
    a11 = e * (1.0f + dt_tau);
    b0  = e * dt_tau2;
    b1  = 1.0f - e * (1.0f + dt_tau);
}

struct C4 { float4 a00, a01, a10, a11, b0, b1; };

__device__ __forceinline__ C4 alpha_coeffs4(float4 t) {
    C4 c;
    alpha_coeffs(t.x, c.a00.x, c.a01.x, c.a10.x, c.a11.x, c.b0.x, c.b1.x);
    alpha_coeffs(t.y, c.a00.y, c.a01.y, c.a10.y, c.a11.y, c.b0.y, c.b1.y);
    alpha_coeffs(t.z, c.a00.z, c.a01.z, c.a10.z, c.a11.z, c.b0.z, c.b1.z);
    alpha_coeffs(t.w, c.a00.w, c.a01.w, c.a10.w, c.a11.w, c.b0.w, c.b1.w);
    return c;
}

__device__ __forceinline__ float4 f4fma(float4 a, float4 b, float4 c) {
    return make_float4(fmaf(a.x,b.x,c.x), fmaf(a.y,b.y,c.y),
                       fmaf(a.z,b.z,c.z), fmaf(a.w,b.w,c.w));
}
__device__ __forceinline__ float4 f4mul(float4 a, float4 b) {
    return make_float4(a.x*b.x, a.y*b.y, a.z*b.z, a.w*b.w);
}
__device__ __forceinline__ float4 f4add(float4 a, float4 b) {
    return make_float4(a.x+b.x, a.y+b.y, a.z+b.z, a.w+b.w);
}
__device__ __forceinline__ float4 f4zero() { return make_float4(0.f,0.f,0.f,0.f); }

// ---- k1: per-chunk local end-states. 1 KiB/wave granule (float4 over K).
// thread g: kq = g&127 (fastest -> 64 lanes = 1 KiB contiguous), b, c above.
// Each thread runs 4 independent chains (k = 4*kq .. 4*kq+3), ring-8 float4.
__global__ __launch_bounds__(kTh, 4) void alpha_k1_states(
    const float* __restrict__ in,
    const float* __restrict__ tau,
    float4* __restrict__ S0,
    float4* __restrict__ S1)
{
    const int g  = blockIdx.x * kTh + threadIdx.x;
    const int kq = g & (kQ - 1);
    const int bc = g >> 7;               // c*kB + b
    const int b  = bc & (kB - 1);
    const int c  = bc >> 6;

    const C4 cf = alpha_coeffs4(((const float4*)tau)[kq]);

    const float4* __restrict__ pin =
        (const float4*)in + ((size_t)b * kT + (size_t)c * kL) * kQ + kq;

    float4 buf[8];
    #pragma unroll
    for (int i = 0; i < 8; ++i) buf[i] = pin[(size_t)i * kQ];

    float4 x0 = f4zero(), x1 = f4zero();
    #pragma unroll
    for (int tb = 0; tb < kL - 8; tb += 8) {
        const float4* __restrict__ pld = pin + (size_t)(tb + 8) * kQ;
        #pragma unroll
        for (int i = 0; i < 8; ++i) {
            const float4 u = buf[i];
            buf[i] = pld[(size_t)i * kQ];
            const float4 n0 = f4fma(cf.a00, x0, f4fma(cf.a01, x1, f4mul(cf.b0, u)));
            const float4 n1 = f4fma(cf.a10, x0, f4fma(cf.a11, x1, f4mul(cf.b1, u)));
            x0 = n0; x1 = n1;
        }
    }
    #pragma unroll
    for (int i = 0; i < 8; ++i) {
        const float4 u = buf[i];
        const float4 n0 = f4fma(cf.a00, x0, f4fma(cf.a01, x1, f4mul(cf.b0, u)));
        const float4 n1 = f4fma(cf.a10, x0, f4fma(cf.a11, x1, f4mul(cf.b1, u)));
        x0 = n0; x1 = n1;
    }

    S0[g] = x0;
    S1[g] = x1;
}

// ---- k2: serial prefix over chunks, in place. S_c -> X_c (entry states).
// thread h = b*kQ + kq (8192 threads). X_0 = (0, il); X_{c+1} = A^32 X_c + S_c.
__global__ __launch_bounds__(kTh, 4) void alpha_k2_prefix(
    const float* __restrict__ init_level,
    const float* __restrict__ tau,
    float4* __restrict__ S0,
    float4* __restrict__ S1)
{
    const int h  = blockIdx.x * kTh + threadIdx.x;   // 0..8191
    const int kq = h & (kQ - 1);
    const int b  = h >> 7;

    const C4 cf = alpha_coeffs4(((const float4*)tau)[kq]);

    // A^32 via 5 element-wise squarings (4 chains per thread).
    float4 m00 = cf.a00, m01 = cf.a01, m10 = cf.a10, m11 = cf.a11;
    #pragma unroll
    for (int s = 0; s < 5; ++s) {
        const float4 t00 = f4fma(m00, m00, f4mul(m01, m10));
        const float4 t01 = f4fma(m00, m01, f4mul(m01, m11));
        const float4 t10 = f4fma(m10, m00, f4mul(m11, m10));
        const float4 t11 = f4fma(m10, m01, f4mul(m11, m11));
        m00 = t00; m01 = t01; m10 = t10; m11 = t11;
    }

    float4 v0 = f4zero();
    float4 v1 = ((const float4*)init_level)[kq];
    size_t idx = (size_t)b * kQ + kq;                // slot of chunk 0
    #pragma unroll
    for (int c = 0; c < kC; ++c) {
        const float4 s0 = S0[idx];
        const float4 s1 = S1[idx];
        S0[idx] = v0;                                // entry state X_c
        S1[idx] = v1;
        const float4 p0 = f4add(f4fma(m00, v0, f4mul(m01, v1)), s0);
        const float4 p1 = f4add(f4fma(m10, v0, f4mul(m11, v1)), s1);
        v0 = p0; v1 = p1;
        idx += (size_t)kB * kQ;                      // next chunk's slot
    }
}

// ---- k3: rescan from entry state (L3-hot re-read), NT output stores. ----
__global__ __launch_bounds__(kTh, 4) void alpha_k3_rescan(
    const float* __restrict__ in,
    const float* __restrict__ tau,
    const float4* __restrict__ S0,
    const float4* __restrict__ S1,
    float* __restrict__ out)
{
    const int g  = blockIdx.x * kTh + threadIdx.x;
    const int kq = g & (kQ - 1);
    const int bc = g >> 7;
    const int b  = bc & (kB - 1);
    const int c  = bc >> 6;

    const C4 cf = alpha_coeffs4(((const float4*)tau)[kq]);

    float4 v0 = S0[g];
    float4 v1 = S1[g];

    const size_t base = ((size_t)b * kT + (size_t)c * kL) * kQ + kq;
    const float4* __restrict__ pin  = (const float4*)in  + base;
    float4* __restrict__ pout       = (float4*)out + base;

    float4 buf[8];
    #pragma unroll
    for (int i = 0; i < 8; ++i) buf[i] = pin[(size_t)i * kQ];

    #pragma unroll
    for (int tb = 0; tb < kL - 8; tb += 8) {
        const float4* __restrict__ pld = pin  + (size_t)(tb + 8) * kQ;
        float4* __restrict__ pst       = pout + (size_t)tb * kQ;
        #pragma unroll
        for (int i = 0; i < 8; ++i) {
            const float4 u = buf[i];
            buf[i] = pld[(size_t)i * kQ];
            const float4 n0 = f4fma(cf.a00, v0, f4fma(cf.a01, v1, f4mul(cf.b0, u)));
            const float4 n1 = f4fma(cf.a10, v0, f4fma(cf.a11, v1, f4mul(cf.b1, u)));
            v0 = n0; v1 = n1;
            nt_store4(n1, &pst[(size_t)i * kQ]);
        }
    }
    {
        float4* __restrict__ pst = pout + (size_t)(kL - 8) * kQ;
        #pragma unroll
        for (int i = 0; i < 8; ++i) {
            const float4 u = buf[i];
            const float4 n0 = f4fma(cf.a00, v0, f4fma(cf.a01, v1, f4mul(cf.b0, u)));
            const float4 n1 = f4fma(cf.a10, v0, f4fma(cf.a11, v1, f4mul(cf.b1, u)));
            v0 = n0; v1 = n1;
            nt_store4(n1, &pst[(size_t)i * kQ]);
        }
    }
}

// ---- fallback: verified single-kernel chunked scan (round-3 kernel). ----
__global__ __launch_bounds__(1024, 8) void alpha_scan_c32(
    const float* __restrict__ in,
    const float* __restrict__ init_level,
    const float* __restrict__ tau,
    float* __restrict__ out)
{
    __shared__ float sx0[32][32];
    __shared__ float sx1[32][32];

    const int tid = threadIdx.x;
    const int kl  = tid & 31;
    const int c   = tid >> 5;
    const int bx  = blockIdx.x;
    const int b   = bx >> 4;
    const int k   = ((bx & 15) << 5) + kl;

    float a00, a01, a10, a11, b0, b1;
    alpha_coeffs(tau[k], a00, a01, a10, a11, b0, b1);
    const float il = init_level[k];

    const size_t base = (size_t)b * kT * kK + (size_t)c * 32 * kK + k;
    const float* __restrict__ pin = in + base;

    float r[32];
    #pragma unroll
    for (int i = 0; i < 32; ++i) r[i] = pin[(size_t)i * kK];

    float x0 = 0.0f, x1 = 0.0f;
    #pragma unroll
    for (int i = 0; i < 32; ++i) {
        const float u   = r[i];
        const float nx0 = fmaf(a00, x0, fmaf(a01, x1, b0 * u));
        const float nx1 = fmaf(a10, x0, fmaf(a11, x1, b1 * u));
        x0 = nx0; x1 = nx1;
        r[i] = nx1;
    }
    sx0[c][kl] = x0;
    sx1[c][kl] = x1;
    __syncthreads();

    float m00 = a00, m01 = a01, m10 = a10, m11 = a11;
    #pragma unroll
    for (int sq = 0; sq < 5; ++sq) {
        const float t00 = fmaf(m00, m00, m01 * m10);
        const float t01 = fmaf(m00, m01, m01 * m11);
        const float t10 = fmaf(m10, m00, m11 * m10);
        const float t11 = fmaf(m10, m01, m11 * m11);
        m00 = t00; m01 = t01; m10 = t10; m11 = t11;
    }
    float v0 = 0.0f, v1 = il;
    for (int j = 0; j < c; ++j) {
        const float p0 = fmaf(m00, v0, m01 * v1) + sx0[j][kl];
        const float p1 = fmaf(m10, v0, m11 * v1) + sx1[j][kl];
        v0 = p0; v1 = p1;
    }
    float* __restrict__ pout = out + base;
    #pragma unroll
    for (int i = 0; i < 32; ++i) {
        const float n0 = fmaf(a00, v0, a01 * v1);
        const float n1 = fmaf(a10, v0, a11 * v1);
        v0 = n0; v1 = n1;
        pout[(size_t)i * kK] = r[i] + n1;
    }
}

extern "C" void kernel_launch(void* const* d_in, const int* in_sizes, int n_in,
                              void* d_out, int out_size, void* d_ws, size_t ws_size,
                              hipStream_t stream) {
    const float* in  = (const float*)d_in[0];   // [64,1024,512] fp32
    const float* il  = (const float*)d_in[1];   // [512] fp32
    const float* tau = (const float*)d_in[2];   // [512] fp32
    float* out = (float*)d_out;                 // [64,1024,512] fp32

    const size_t ws_needed = (size_t)kG * 2 * sizeof(float4);   // 8 MiB
    if (d_ws != nullptr && ws_size >= ws_needed) {
        float4* S0 = (float4*)d_ws;
        float4* S1 = S0 + kG;
        alpha_k1_states<<<dim3(kG / kTh), dim3(kTh), 0, stream>>>(in, tau, S0, S1);
        alpha_k2_prefix<<<dim3((kB * kQ) / kTh), dim3(kTh), 0, stream>>>(il, tau, S0, S1);
        alpha_k3_rescan<<<dim3(kG / kTh), dim3(kTh), 0, stream>>>(in, tau, S0, S1, out);
    } else {
        alpha_scan_c32<<<dim3(kB * (kK / 32)), dim3(1024), 0, stream>>>(
            in, il, tau, out);
    }
}

// Round 9
// 261.486 us; speedup vs baseline: 1.0162x; 1.0162x over previous
//
#include <hip/hip_runtime.h>
#include <math.h>

namespace {
constexpr int kB  = 64, kT = 1024, kK = 512;
constexpr int kC  = 32;              // chunks along T
constexpr int kL  = kT / kC;         // 32 steps per chunk
constexpr int kQ  = kK / 4;          // 128 float4-groups along K
constexpr int kQT = 32;              // float4-groups per fused block
constexpr int kTh = 256;             // threads per block (k1)
constexpr int kG1 = kB * (kC - 1) * kQ;   // k1 threads (chunk 31 end-state unused)
constexpr float kDT = 0.001f;
}

// Native vector type for nontemporal stores (HIP float4 is a class type
// that __builtin_nontemporal_store rejects; this is layout-identical).
typedef float nt4 __attribute__((ext_vector_type(4)));

__device__ __forceinline__ void nt_store4(float4 v, float4* p) {
    nt4 w; w.x = v.x; w.y = v.y; w.z = v.z; w.w = v.w;
    __builtin_nontemporal_store(w, (nt4*)p);
}

// Per-feature coefficients (identical arithmetic to the reference).
__device__ __forceinline__ void alpha_coeffs(float tk,
    float& a00, float& a01, float& a10, float& a11, float& b0, float& b1)
{
    const float tc      = fmaxf(tk, 1e-8f);
    const float dt_tau  = kDT / tc;
    const float dt_tau2 = dt_tau / tc;
    const float e       = expf(-dt_tau);
    a00 = e * (1.0f - dt_tau);
    a01 = e * (-dt_tau2);
    a10 = e * kDT;
    a11 = e * (1.0f + dt_tau);
    b0  = e * dt_tau2;
    b1  = 1.0f - e * (1.0f + dt_tau);
}

struct C4 { float4 a00, a01, a10, a11, b0, b1; };

__device__ __forceinline__ C4 alpha_coeffs4(float4 t) {
    C4 c;
    alpha_coeffs(t.x, c.a00.x, c.a01.x, c.a10.x, c.a11.x, c.b0.x, c.b1.x);
    alpha_coeffs(t.y, c.a00.y, c.a01.y, c.a10.y, c.a11.y, c.b0.y, c.b1.y);
    alpha_coeffs(t.z, c.a00.z, c.a01.z, c.a10.z, c.a11.z, c.b0.z, c.b1.z);
    alpha_coeffs(t.w, c.a00.w, c.a01.w, c.a10.w, c.a11.w, c.b0.w, c.b1.w);
    return c;
}

__device__ __forceinline__ float4 f4fma(float4 a, float4 b, float4 c) {
    return make_float4(fmaf(a.x,b.x,c.x), fmaf(a.y,b.y,c.y),
                       fmaf(a.z,b.z,c.z), fmaf(a.w,b.w,c.w));
}
__device__ __forceinline__ float4 f4mul(float4 a, float4 b) {
    return make_float4(a.x*b.x, a.y*b.y, a.z*b.z, a.w*b.w);
}
__device__ __forceinline__ float4 f4add(float4 a, float4 b) {
    return make_float4(a.x+b.x, a.y+b.y, a.z+b.z, a.w+b.w);
}
__device__ __forceinline__ float4 f4zero() { return make_float4(0.f,0.f,0.f,0.f); }

// ---- k1: per-chunk local end-states for chunks 0..30 (chunk 31's end state
// is never consumed). 1 KiB/wave read granule; ring-8 float4; cached loads
// deliberately stage the input in L3 for k2f's re-read.
__global__ __launch_bounds__(kTh, 4) void alpha_k1_states(
    const float* __restrict__ in,
    const float* __restrict__ tau,
    float4* __restrict__ S0,
    float4* __restrict__ S1)
{
    const int g  = blockIdx.x * kTh + threadIdx.x;   // 0..kG1-1
    const int kq = g & (kQ - 1);
    const int bc = g >> 7;               // c*kB + b, c in 0..30
    const int b  = bc & (kB - 1);
    const int c  = bc >> 6;

    const C4 cf = alpha_coeffs4(((const float4*)tau)[kq]);

    const float4* __restrict__ pin =
        (const float4*)in + ((size_t)b * kT + (size_t)c * kL) * kQ + kq;

    float4 buf[8];
    #pragma unroll
    for (int i = 0; i < 8; ++i) buf[i] = pin[(size_t)i * kQ];

    float4 x0 = f4zero(), x1 = f4zero();
    #pragma unroll
    for (int tb = 0; tb < kL - 8; tb += 8) {
        const float4* __restrict__ pld = pin + (size_t)(tb + 8) * kQ;
        #pragma unroll
        for (int i = 0; i < 8; ++i) {
            const float4 u = buf[i];
            buf[i] = pld[(size_t)i * kQ];
            const float4 n0 = f4fma(cf.a00, x0, f4fma(cf.a01, x1, f4mul(cf.b0, u)));
            const float4 n1 = f4fma(cf.a10, x0, f4fma(cf.a11, x1, f4mul(cf.b1, u)));
            x0 = n0; x1 = n1;
        }
    }
    #pragma unroll
    for (int i = 0; i < 8; ++i) {
        const float4 u = buf[i];
        const float4 n0 = f4fma(cf.a00, x0, f4fma(cf.a01, x1, f4mul(cf.b0, u)));
        const float4 n1 = f4fma(cf.a10, x0, f4fma(cf.a11, x1, f4mul(cf.b1, u)));
        x0 = n0; x1 = n1;
    }

    S0[g] = x0;   // index (c*kB + b)*kQ + kq
    S1[g] = x1;
}

// ---- k2f: fused LDS prefix + rescan, NT output stores. ------------------
// Block = 32 chunks x 32 float4-groups (1024 thr), grid = 64 b x 4 kq-tiles
// = 256 blocks = exactly 1 block/CU (16 waves). Phase A: S -> LDS.
// Phase B: A^32 (5 squarings) + per-thread serial prefix over LDS (wave
// divergence <= 1 iteration: each wave holds chunks c, c+1). Phase C:
// ring-8 float4 rescan from the true entry state -- the input re-read is
// L3-hot (k1 cached it; only 16 MB of S moved since; NT stores bypass L3
// so the 134 MB output stream cannot evict it).
__global__ __launch_bounds__(1024, 4) void alpha_k2_fused(
    const float* __restrict__ in,
    const float* __restrict__ init_level,
    const float* __restrict__ tau,
    const float4* __restrict__ S0,
    const float4* __restrict__ S1,
    float* __restrict__ out)
{
    __shared__ float4 ls0[kC][kQT];      // 16 KB
    __shared__ float4 ls1[kC][kQT];      // 16 KB

    const int tid = threadIdx.x;
    const int kqi = tid & (kQT - 1);     // 0..31 (fast -> coalesced)
    const int c   = tid >> 5;            // chunk 0..31
    const int bx  = blockIdx.x;
    const int b   = bx >> 2;             // / (kQ/kQT = 4)
    const int kq  = ((bx & 3) << 5) + kqi;

    const C4 cf = alpha_coeffs4(((const float4*)tau)[kq]);
    const float4 il = ((const float4*)init_level)[kq];

    // Phase A: chunk end-states (c <= 30) into LDS.
    if (c < kC - 1) {
        const size_t sidx = (size_t)(c * kB + b) * kQ + kq;
        ls0[c][kqi] = S0[sidx];
        ls1[c][kqi] = S1[sidx];
    }
    __syncthreads();

    // Phase B: A^32 via 5 squarings, then serial prefix over j < c.
    float4 m00 = cf.a00, m01 = cf.a01, m10 = cf.a10, m11 = cf.a11;
    #pragma unroll
    for (int s = 0; s < 5; ++s) {
        const float4 t00 = f4fma(m00, m00, f4mul(m01, m10));
        const float4 t01 = f4fma(m00, m01, f4mul(m01, m11));
        const float4 t10 = f4fma(m10, m00, f4mul(m11, m10));
        const float4 t11 = f4fma(m10, m01, f4mul(m11, m11));
        m00 = t00; m01 = t01; m10 = t10; m11 = t11;
    }
    float4 v0 = f4zero(), v1 = il;       // state entering chunk 0
    for (int j = 0; j < c; ++j) {
        const float4 p0 = f4add(f4fma(m00, v0, f4mul(m01, v1)), ls0[j][kqi]);
        const float4 p1 = f4add(f4fma(m10, v0, f4mul(m11, v1)), ls1[j][kqi]);
        v0 = p0; v1 = p1;
    }
    // (v0,v1) = true state entering chunk c.

    // Phase C: ring-8 rescan from entry state; NT stores.
    const size_t base = ((size_t)b * kT + (size_t)c * kL) * kQ + kq;
    const float4* __restrict__ pin  = (const float4*)in  + base;
    float4* __restrict__ pout       = (float4*)out + base;

    float4 buf[8];
    #pragma unroll
    for (int i = 0; i < 8; ++i) buf[i] = pin[(size_t)i * kQ];

    #pragma unroll
    for (int tb = 0; tb < kL - 8; tb += 8) {
        const float4* __restrict__ pld = pin  + (size_t)(tb + 8) * kQ;
        float4* __restrict__ pst       = pout + (size_t)tb * kQ;
        #pragma unroll
        for (int i = 0; i < 8; ++i) {
            const float4 u = buf[i];
            buf[i] = pld[(size_t)i * kQ];
            const float4 n0 = f4fma(cf.a00, v0, f4fma(cf.a01, v1, f4mul(cf.b0, u)));
            const float4 n1 = f4fma(cf.a10, v0, f4fma(cf.a11, v1, f4mul(cf.b1, u)));
            v0 = n0; v1 = n1;
            nt_store4(n1, &pst[(size_t)i * kQ]);
        }
    }
    {
        float4* __restrict__ pst = pout + (size_t)(kL - 8) * kQ;
        #pragma unroll
        for (int i = 0; i < 8; ++i) {
            const float4 u = buf[i];
            const float4 n0 = f4fma(cf.a00, v0, f4fma(cf.a01, v1, f4mul(cf.b0, u)));
            const float4 n1 = f4fma(cf.a10, v0, f4fma(cf.a11, v1, f4mul(cf.b1, u)));
            v0 = n0; v1 = n1;
            nt_store4(n1, &pst[(size_t)i * kQ]);
        }
    }
}

// ---- fallback: verified single-kernel chunked scan (round-3 kernel). ----
__global__ __launch_bounds__(1024, 8) void alpha_scan_c32(
    const float* __restrict__ in,
    const float* __restrict__ init_level,
    const float* __restrict__ tau,
    float* __restrict__ out)
{
    __shared__ float sx0[32][32];
    __shared__ float sx1[32][32];

    const int tid = threadIdx.x;
    const int kl  = tid & 31;
    const int c   = tid >> 5;
    const int bx  = blockIdx.x;
    const int b   = bx >> 4;
    const int k   = ((bx & 15) << 5) + kl;

    float a00, a01, a10, a11, b0, b1;
    alpha_coeffs(tau[k], a00, a01, a10, a11, b0, b1);
    const float il = init_level[k];

    const size_t base = (size_t)b * kT * kK + (size_t)c * 32 * kK + k;
    const float* __restrict__ pin = in + base;

    float r[32];
    #pragma unroll
    for (int i = 0; i < 32; ++i) r[i] = pin[(size_t)i * kK];

    float x0 = 0.0f, x1 = 0.0f;
    #pragma unroll
    for (int i = 0; i < 32; ++i) {
        const float u   = r[i];
        const float nx0 = fmaf(a00, x0, fmaf(a01, x1, b0 * u));
        const float nx1 = fmaf(a10, x0, fmaf(a11, x1, b1 * u));
        x0 = nx0; x1 = nx1;
        r[i] = nx1;
    }
    sx0[c][kl] = x0;
    sx1[c][kl] = x1;
    __syncthreads();

    float m00 = a00, m01 = a01, m10 = a10, m11 = a11;
    #pragma unroll
    for (int sq = 0; sq < 5; ++sq) {
        const float t00 = fmaf(m00, m00, m01 * m10);
        const float t01 = fmaf(m00, m01, m01 * m11);
        const float t10 = fmaf(m10, m00, m11 * m10);
        const float t11 = fmaf(m10, m01, m11 * m11);
        m00 = t00; m01 = t01; m10 = t10; m11 = t11;
    }
    float v0 = 0.0f, v1 = il;
    for (int j = 0; j < c; ++j) {
        const float p0 = fmaf(m00, v0, m01 * v1) + sx0[j][kl];
        const float p1 = fmaf(m10, v0, m11 * v1) + sx1[j][kl];
        v0 = p0; v1 = p1;
    }
    float* __restrict__ pout = out + base;
    #pragma unroll
    for (int i = 0; i < 32; ++i) {
        const float n0 = fmaf(a00, v0, a01 * v1);
        const float n1 = fmaf(a10, v0, a11 * v1);
        v0 = n0; v1 = n1;
        pout[(size_t)i * kK] = r[i] + n1;
    }
}

extern "C" void kernel_launch(void* const* d_in, const int* in_sizes, int n_in,
                              void* d_out, int out_size, void* d_ws, size_t ws_size,
                              hipStream_t stream) {
    const float* in  = (const float*)d_in[0];   // [64,1024,512] fp32
    const float* il  = (const float*)d_in[1];   // [512] fp32
    const float* tau = (const float*)d_in[2];   // [512] fp32
    float* out = (float*)d_out;                 // [64,1024,512] fp32

    const size_t ws_needed = (size_t)kC * kB * kQ * 2 * sizeof(float4); // 8 MiB
    if (d_ws != nullptr && ws_size >= ws_needed) {
        float4* S0 = (float4*)d_ws;
        float4* S1 = S0 + (size_t)kC * kB * kQ;
        alpha_k1_states<<<dim3(kG1 / kTh), dim3(kTh), 0, stream>>>(in, tau, S0, S1);
        alpha_k2_fused<<<dim3(kB * (kQ / kQT)), dim3(1024), 0, stream>>>(
            in, il, tau, S0, S1, out);
    } else {
        alpha_scan_c32<<<dim3(kB * (kK / 32)), dim3(1024), 0, stream>>>(
            in, il, tau, out);
    }
}